// Round 1
// baseline (1252.458 us; speedup 1.0000x reference)
//
#include <hip/hip_runtime.h>
#include <math.h>

#define NT   256     // threads per block
#define GB   2       // batch elements per block
#define NTOK 20

// ---------------------------------------------------------------------------
// Generic per-token layer: out[b][c][n] = act(bias[c] + sum_k in[b][k][n] * W[k][c])
// LDS layouts: act = [GB][K][NTOK], out = [GB][OUT][NTOK]
// Thread <-> (b, c) task; acc[20] held as 5 x float4 in registers.
// Weight read: W[k*OUT + c] -> coalesced across threads (consecutive c), L2-resident.
// Activation read: 20 contiguous floats (5 x ds_read_b128), broadcast across
// threads that share b.
// ---------------------------------------------------------------------------
template <int K, int OUT, bool RELU>
__device__ __forceinline__ void layer_tok(const float* __restrict__ W,
                                          const float* __restrict__ bias,
                                          const float* act, float* out, int tid)
{
    for (int t = tid; t < GB * OUT; t += NT) {
        int b = t / OUT, c = t % OUT;
        float4 acc[5];
#pragma unroll
        for (int i = 0; i < 5; ++i) acc[i] = make_float4(0.f, 0.f, 0.f, 0.f);
        const float* ab = act + b * K * NTOK;
#pragma unroll 2
        for (int k = 0; k < K; ++k) {
            float w = W[k * OUT + c];
            const float4* a4 = reinterpret_cast<const float4*>(ab + k * NTOK);
#pragma unroll
            for (int i = 0; i < 5; ++i) {
                float4 v = a4[i];
                acc[i].x = fmaf(v.x, w, acc[i].x);
                acc[i].y = fmaf(v.y, w, acc[i].y);
                acc[i].z = fmaf(v.z, w, acc[i].z);
                acc[i].w = fmaf(v.w, w, acc[i].w);
            }
        }
        float bs = bias[c];
        float* ob = out + t * NTOK;   // (b*OUT + c) * NTOK
#pragma unroll
        for (int i = 0; i < 5; ++i) {
            float4 v = acc[i];
            v.x += bs; v.y += bs; v.z += bs; v.w += bs;
            if (RELU) {
                v.x = fmaxf(v.x, 0.f); v.y = fmaxf(v.y, 0.f);
                v.z = fmaxf(v.z, 0.f); v.w = fmaxf(v.w, 0.f);
            }
            reinterpret_cast<float4*>(ob)[i] = v;
        }
    }
}

// Per-batch vector layer: out[b][c] = act(bias[c] + sum_k in[b][k] * W[k][c])
template <int K, int OUT, bool RELU>
__device__ __forceinline__ void layer_vec(const float* __restrict__ W,
                                          const float* __restrict__ bias,
                                          const float* in, float* out, int tid)
{
    for (int t = tid; t < GB * OUT; t += NT) {
        int b = t / OUT, c = t % OUT;
        float acc = bias[c];
        const float* ib = in + b * K;
#pragma unroll 4
        for (int k = 0; k < K; ++k) acc = fmaf(ib[k], W[k * OUT + c], acc);
        out[t] = RELU ? fmaxf(acc, 0.f) : acc;
    }
}

__global__ __launch_bounds__(NT)
void vnet_kernel(const float* __restrict__ x,
                 const float* __restrict__ w1a, const float* __restrict__ b1a,
                 const float* __restrict__ w1b, const float* __restrict__ b1b,
                 const float* __restrict__ wa0, const float* __restrict__ ba0,
                 const float* __restrict__ wa1, const float* __restrict__ ba1,
                 const float* __restrict__ wa2, const float* __restrict__ ba2,
                 const float* __restrict__ w2a, const float* __restrict__ b2a,
                 const float* __restrict__ w2b, const float* __restrict__ b2b,
                 const float* __restrict__ w3a, const float* __restrict__ b3a,
                 const float* __restrict__ w3b, const float* __restrict__ b3b,
                 const float* __restrict__ w3c, const float* __restrict__ b3c,
                 const float* __restrict__ w3d, const float* __restrict__ b3d,
                 float* __restrict__ outp)
{
    // LDS activations, all [b][feature][token] (token contiguous, 80B rows)
    __shared__ __align__(16) float xs [GB * 13  * NTOK];  // x transposed
    __shared__ __align__(16) float t1 [GB * 150 * NTOK];
    __shared__ __align__(16) float h1 [GB * 100 * NTOK];
    __shared__ __align__(16) float gq [GB * 100];         // mean over tokens
    __shared__ __align__(16) float sc1[GB * 100 * NTOK];  // s1, then f1
    __shared__ __align__(16) float sc2[GB * 100 * NTOK];  // s2, then f
    __shared__ __align__(16) float att[GB * NTOK];        // scores -> attn
    __shared__ __align__(16) float mv [GB * 56];          // [self_state | wf]
    __shared__ __align__(16) float ha [GB * 150];
    __shared__ __align__(16) float hb [GB * 100];
    __shared__ __align__(16) float hc [GB * 100];

    const int tid = threadIdx.x;
    const int b0  = blockIdx.x * GB;

    // ---- load + transpose x: xs[b][d][n] = x[b0+b][n][d] -----------------
    const float* xg = x + (size_t)b0 * (NTOK * 13);
    for (int t = tid; t < GB * NTOK * 13; t += NT) {
        int b = t / (NTOK * 13), r = t % (NTOK * 13);
        int n = r / 13, d = r % 13;
        xs[(b * 13 + d) * NTOK + n] = xg[t];   // coalesced read
    }
    __syncthreads();

    // ---- h1 = relu(relu(x@w1a+b1a)@w1b+b1b) ------------------------------
    layer_tok<13, 150, true>(w1a, b1a, xs, t1, tid);
    __syncthreads();
    layer_tok<150, 100, true>(w1b, b1b, t1, h1, tid);
    __syncthreads();

    // ---- g = mean over tokens --------------------------------------------
    for (int t = tid; t < GB * 100; t += NT) {
        const float* hr = h1 + t * NTOK;
        float s = 0.f;
#pragma unroll
        for (int n = 0; n < NTOK; ++n) s += hr[n];
        gq[t] = s * (1.f / NTOK);
    }
    __syncthreads();

    // ---- s1 = relu([h1 | g] @ wa0 + ba0) ---------------------------------
    // g-part is token-independent -> single dot per (b,c)
    for (int t = tid; t < GB * 100; t += NT) {
        int b = t / 100, c = t % 100;
        float gacc = ba0[c];
        const float* gb_ = gq + b * 100;
#pragma unroll 4
        for (int k = 0; k < 100; ++k)
            gacc = fmaf(gb_[k], wa0[(100 + k) * 100 + c], gacc);
        float4 acc[5];
#pragma unroll
        for (int i = 0; i < 5; ++i) acc[i] = make_float4(0.f, 0.f, 0.f, 0.f);
        const float* ab = h1 + b * 100 * NTOK;
#pragma unroll 2
        for (int k = 0; k < 100; ++k) {
            float w = wa0[k * 100 + c];
            const float4* a4 = reinterpret_cast<const float4*>(ab + k * NTOK);
#pragma unroll
            for (int i = 0; i < 5; ++i) {
                float4 v = a4[i];
                acc[i].x = fmaf(v.x, w, acc[i].x);
                acc[i].y = fmaf(v.y, w, acc[i].y);
                acc[i].z = fmaf(v.z, w, acc[i].z);
                acc[i].w = fmaf(v.w, w, acc[i].w);
            }
        }
        float* ob = sc1 + t * NTOK;
#pragma unroll
        for (int i = 0; i < 5; ++i) {
            float4 v = acc[i];
            v.x = fmaxf(v.x + gacc, 0.f); v.y = fmaxf(v.y + gacc, 0.f);
            v.z = fmaxf(v.z + gacc, 0.f); v.w = fmaxf(v.w + gacc, 0.f);
            reinterpret_cast<float4*>(ob)[i] = v;
        }
    }
    __syncthreads();

    // ---- s2 = relu(s1 @ wa1 + ba1) ---------------------------------------
    layer_tok<100, 100, true>(wa1, ba1, sc1, sc2, tid);
    __syncthreads();

    // ---- scores = s2 @ wa2 + ba2 -----------------------------------------
    for (int t = tid; t < GB * NTOK; t += NT) {
        int b = t / NTOK, n = t % NTOK;
        float acc = ba2[0];
        const float* sb = sc2 + b * 100 * NTOK + n;
#pragma unroll 4
        for (int c = 0; c < 100; ++c) acc = fmaf(sb[c * NTOK], wa2[c], acc);
        att[t] = acc;
    }
    __syncthreads();

    // ---- softmax over tokens (serial per b; tiny) ------------------------
    if (tid < GB) {
        float* a = att + tid * NTOK;
        float mx = a[0];
#pragma unroll
        for (int n = 1; n < NTOK; ++n) mx = fmaxf(mx, a[n]);
        float s = 0.f;
#pragma unroll
        for (int n = 0; n < NTOK; ++n) { float e = expf(a[n] - mx); a[n] = e; s += e; }
        float inv = 1.f / s;
#pragma unroll
        for (int n = 0; n < NTOK; ++n) a[n] *= inv;
    }
    __syncthreads();

    // ---- f = relu(h1 @ w2a + b2a) @ w2b + b2b ----------------------------
    layer_tok<100, 100, true>(w2a, b2a, h1, sc1, tid);   // f1 -> sc1
    __syncthreads();
    layer_tok<100, 50, false>(w2b, b2b, sc1, sc2, tid);  // f  -> sc2
    __syncthreads();

    // ---- m = [self_state | wf],  wf[b][c] = sum_n f[b][c][n] * attn[b][n]
    if (tid < GB * 56) {
        int b = tid / 56, c = tid % 56;
        float v;
        if (c < 6) {
            v = xs[(b * 13 + c) * NTOK + 0];   // x[b,0,c]
        } else {
            int cc = c - 6;
            const float* fb = sc2 + (b * 50 + cc) * NTOK;
            const float* ab = att + b * NTOK;
            float acc = 0.f;
#pragma unroll
            for (int n = 0; n < NTOK; ++n) acc = fmaf(fb[n], ab[n], acc);
            v = acc;
        }
        mv[tid] = v;
    }
    __syncthreads();

    // ---- final MLP: 56 -> 150 -> 100 -> 100 -> 1 -------------------------
    layer_vec<56, 150, true>(w3a, b3a, mv, ha, tid);
    __syncthreads();
    layer_vec<150, 100, true>(w3b, b3b, ha, hb, tid);
    __syncthreads();
    layer_vec<100, 100, true>(w3c, b3c, hb, hc, tid);
    __syncthreads();

    if (tid < GB) {
        const float* ib = hc + tid * 100;
        float acc = b3d[0];
#pragma unroll 4
        for (int k = 0; k < 100; ++k) acc = fmaf(ib[k], w3d[k], acc);
        outp[b0 + tid] = acc;
    }
}

extern "C" void kernel_launch(void* const* d_in, const int* in_sizes, int n_in,
                              void* d_out, int out_size, void* d_ws, size_t ws_size,
                              hipStream_t stream)
{
    const float* x   = (const float*)d_in[0];
    const float* w1a = (const float*)d_in[1];
    const float* b1a = (const float*)d_in[2];
    const float* w1b = (const float*)d_in[3];
    const float* b1b = (const float*)d_in[4];
    const float* wa0 = (const float*)d_in[5];
    const float* ba0 = (const float*)d_in[6];
    const float* wa1 = (const float*)d_in[7];
    const float* ba1 = (const float*)d_in[8];
    const float* wa2 = (const float*)d_in[9];
    const float* ba2 = (const float*)d_in[10];
    const float* w2a = (const float*)d_in[11];
    const float* b2a = (const float*)d_in[12];
    const float* w2b = (const float*)d_in[13];
    const float* b2b = (const float*)d_in[14];
    const float* w3a = (const float*)d_in[15];
    const float* b3a = (const float*)d_in[16];
    const float* w3b = (const float*)d_in[17];
    const float* b3b = (const float*)d_in[18];
    const float* w3c = (const float*)d_in[19];
    const float* b3c = (const float*)d_in[20];
    const float* w3d = (const float*)d_in[21];
    const float* b3d = (const float*)d_in[22];
    float* outp = (float*)d_out;

    const int B = 16384;
    dim3 grid(B / GB), block(NT);
    hipLaunchKernelGGL(vnet_kernel, grid, block, 0, stream,
                       x, w1a, b1a, w1b, b1b, wa0, ba0, wa1, ba1, wa2, ba2,
                       w2a, b2a, w2b, b2b, w3a, b3a, w3b, b3b, w3c, b3c,
                       w3d, b3d, outp);
}

// Round 2
// 817.400 us; speedup vs baseline: 1.5322x; 1.5322x over previous
//
#include <hip/hip_runtime.h>
#include <math.h>

#define NT   256     // threads per block
#define GB   2       // batch elements per block
#define NTOK 20

// LDS arena (floats):
//   A [0 .. 4000)        : h1  (GB*100*NTOK)                       16000 B
//   B [4000 .. 12000)    : t1 (6000) | later s1/f1 (4000) + s2/f (4000)
//                          | later mv/ha/hb/hc                     32000 B
//   D [12000 .. 13040)   : xs (1040) | later gq(200)+att(40)+ss(12) 4160 B
// total 13040 floats = 52160 B  -> 3 blocks/CU (12 waves/CU)
#define OFF_H1   0
#define OFF_B    4000
#define OFF_T1   (OFF_B)          // 6000 floats
#define OFF_SC1  (OFF_B)          // 4000 floats (s1, then f1)
#define OFF_SC2  (OFF_B + 4000)   // 4000 floats (s2, then f)
#define OFF_MV   (OFF_B)          // 112 floats
#define OFF_HA   (OFF_B + 128)    // 300
#define OFF_HB   (OFF_B + 448)    // 200
#define OFF_HC   (OFF_B + 672)    // 200
#define OFF_D    12000
#define OFF_XS   (OFF_D)          // 1040 floats
#define OFF_GQ   (OFF_D)          // 200 floats (overwrites dead xs)
#define OFF_ATT  (OFF_D + 208)    // 40 floats
#define OFF_SS   (OFF_D + 1024)   // 12 floats (self_state, 2 x 6)
#define LDS_FLOATS 13040

// ---------------------------------------------------------------------------
// Per-token layer: out[b][c][n] = act(bias[c] + sum_k in[b][k][n] * W[k][c])
// act = [GB][K][NTOK], out = [GB][OUT][NTOK]; thread <-> (b,c) task.
// unroll 8 keeps ~8 weight loads in flight to hide L1/L2 latency.
// ---------------------------------------------------------------------------
template <int K, int OUT, bool RELU>
__device__ __forceinline__ void layer_tok(const float* __restrict__ W,
                                          const float* __restrict__ bias,
                                          const float* act, float* out, int tid)
{
    for (int t = tid; t < GB * OUT; t += NT) {
        int b = t / OUT, c = t % OUT;
        float4 acc[5];
#pragma unroll
        for (int i = 0; i < 5; ++i) acc[i] = make_float4(0.f, 0.f, 0.f, 0.f);
        const float* ab = act + b * K * NTOK;
#pragma unroll 8
        for (int k = 0; k < K; ++k) {
            float w = W[k * OUT + c];
            const float4* a4 = reinterpret_cast<const float4*>(ab + k * NTOK);
#pragma unroll
            for (int i = 0; i < 5; ++i) {
                float4 v = a4[i];
                acc[i].x = fmaf(v.x, w, acc[i].x);
                acc[i].y = fmaf(v.y, w, acc[i].y);
                acc[i].z = fmaf(v.z, w, acc[i].z);
                acc[i].w = fmaf(v.w, w, acc[i].w);
            }
        }
        float bs = bias[c];
        float* ob = out + (b * OUT + c) * NTOK;
#pragma unroll
        for (int i = 0; i < 5; ++i) {
            float4 v = acc[i];
            v.x += bs; v.y += bs; v.z += bs; v.w += bs;
            if (RELU) {
                v.x = fmaxf(v.x, 0.f); v.y = fmaxf(v.y, 0.f);
                v.z = fmaxf(v.z, 0.f); v.w = fmaxf(v.w, 0.f);
            }
            reinterpret_cast<float4*>(ob)[i] = v;
        }
    }
}

// Per-batch vector layer: out[b][c] = act(bias[c] + sum_k in[b][k] * W[k][c])
template <int K, int OUT, bool RELU>
__device__ __forceinline__ void layer_vec(const float* __restrict__ W,
                                          const float* __restrict__ bias,
                                          const float* in, float* out, int tid)
{
    for (int t = tid; t < GB * OUT; t += NT) {
        int b = t / OUT, c = t % OUT;
        float acc = bias[c];
        const float* ib = in + b * K;
#pragma unroll 8
        for (int k = 0; k < K; ++k) acc = fmaf(ib[k], W[k * OUT + c], acc);
        out[t] = RELU ? fmaxf(acc, 0.f) : acc;
    }
}

__global__ __launch_bounds__(NT)
void vnet_kernel(const float* __restrict__ x,
                 const float* __restrict__ w1a, const float* __restrict__ b1a,
                 const float* __restrict__ w1b, const float* __restrict__ b1b,
                 const float* __restrict__ wa0, const float* __restrict__ ba0,
                 const float* __restrict__ wa1, const float* __restrict__ ba1,
                 const float* __restrict__ wa2, const float* __restrict__ ba2,
                 const float* __restrict__ w2a, const float* __restrict__ b2a,
                 const float* __restrict__ w2b, const float* __restrict__ b2b,
                 const float* __restrict__ w3a, const float* __restrict__ b3a,
                 const float* __restrict__ w3b, const float* __restrict__ b3b,
                 const float* __restrict__ w3c, const float* __restrict__ b3c,
                 const float* __restrict__ w3d, const float* __restrict__ b3d,
                 float* __restrict__ outp)
{
    __shared__ __align__(16) float lds[LDS_FLOATS];
    float* xs  = lds + OFF_XS;
    float* t1  = lds + OFF_T1;
    float* h1  = lds + OFF_H1;
    float* gq  = lds + OFF_GQ;
    float* sc1 = lds + OFF_SC1;
    float* sc2 = lds + OFF_SC2;
    float* att = lds + OFF_ATT;
    float* ss  = lds + OFF_SS;
    float* mv  = lds + OFF_MV;
    float* ha  = lds + OFF_HA;
    float* hb  = lds + OFF_HB;
    float* hc  = lds + OFF_HC;

    const int tid = threadIdx.x;
    const int b0  = blockIdx.x * GB;

    // ---- phase 1: load + transpose x: xs[b][d][n] = x[b0+b][n][d] --------
    const float* xg = x + (size_t)b0 * (NTOK * 13);
    for (int t = tid; t < GB * NTOK * 13; t += NT) {
        int b = t / (NTOK * 13), r = t % (NTOK * 13);
        int n = r / 13, d = r % 13;
        xs[(b * 13 + d) * NTOK + n] = xg[t];   // coalesced read
    }
    __syncthreads();

    // ---- t1 = relu(x@w1a+b1a) -------------------------------------------
    layer_tok<13, 150, true>(w1a, b1a, xs, t1, tid);
    __syncthreads();
    // ---- h1 = relu(t1@w1b+b1b); also stash self_state (xs last use) -----
    layer_tok<150, 100, true>(w1b, b1b, t1, h1, tid);
    if (tid < GB * 6) {                      // ss[b*6+c] = x[b,0,c]
        int b = tid / 6, c = tid % 6;
        ss[tid] = xs[(b * 13 + c) * NTOK + 0];
    }
    __syncthreads();

    // ---- gq = mean over tokens (overwrites dead xs region) ---------------
    for (int t = tid; t < GB * 100; t += NT) {
        const float* hr = h1 + t * NTOK;
        float s = 0.f;
#pragma unroll
        for (int n = 0; n < NTOK; ++n) s += hr[n];
        gq[t] = s * (1.f / NTOK);
    }
    __syncthreads();

    // ---- s1 = relu([h1 | g] @ wa0 + ba0)  (overwrites dead t1) -----------
    for (int t = tid; t < GB * 100; t += NT) {
        int b = t / 100, c = t % 100;
        float gacc = ba0[c];
        const float* gb_ = gq + b * 100;
#pragma unroll 8
        for (int k = 0; k < 100; ++k)
            gacc = fmaf(gb_[k], wa0[(100 + k) * 100 + c], gacc);
        float4 acc[5];
#pragma unroll
        for (int i = 0; i < 5; ++i) acc[i] = make_float4(0.f, 0.f, 0.f, 0.f);
        const float* ab = h1 + b * 100 * NTOK;
#pragma unroll 8
        for (int k = 0; k < 100; ++k) {
            float w = wa0[k * 100 + c];
            const float4* a4 = reinterpret_cast<const float4*>(ab + k * NTOK);
#pragma unroll
            for (int i = 0; i < 5; ++i) {
                float4 v = a4[i];
                acc[i].x = fmaf(v.x, w, acc[i].x);
                acc[i].y = fmaf(v.y, w, acc[i].y);
                acc[i].z = fmaf(v.z, w, acc[i].z);
                acc[i].w = fmaf(v.w, w, acc[i].w);
            }
        }
        float* ob = sc1 + (b * 100 + c) * NTOK;
#pragma unroll
        for (int i = 0; i < 5; ++i) {
            float4 v = acc[i];
            v.x = fmaxf(v.x + gacc, 0.f); v.y = fmaxf(v.y + gacc, 0.f);
            v.z = fmaxf(v.z + gacc, 0.f); v.w = fmaxf(v.w + gacc, 0.f);
            reinterpret_cast<float4*>(ob)[i] = v;
        }
    }
    __syncthreads();

    // ---- s2 = relu(s1 @ wa1 + ba1) ---------------------------------------
    layer_tok<100, 100, true>(wa1, ba1, sc1, sc2, tid);
    __syncthreads();

    // ---- scores = s2 @ wa2 + ba2 -----------------------------------------
    for (int t = tid; t < GB * NTOK; t += NT) {
        int b = t / NTOK, n = t % NTOK;
        float acc = ba2[0];
        const float* sb = sc2 + b * 100 * NTOK + n;
#pragma unroll 8
        for (int c = 0; c < 100; ++c) acc = fmaf(sb[c * NTOK], wa2[c], acc);
        att[t] = acc;
    }
    __syncthreads();

    // ---- softmax over tokens (serial per b; tiny) ------------------------
    if (tid < GB) {
        float* a = att + tid * NTOK;
        float mx = a[0];
#pragma unroll
        for (int n = 1; n < NTOK; ++n) mx = fmaxf(mx, a[n]);
        float s = 0.f;
#pragma unroll
        for (int n = 0; n < NTOK; ++n) { float e = expf(a[n] - mx); a[n] = e; s += e; }
        float inv = 1.f / s;
#pragma unroll
        for (int n = 0; n < NTOK; ++n) a[n] *= inv;
    }
    __syncthreads();

    // ---- f1 = relu(h1 @ w2a + b2a) (overwrites dead s1) ------------------
    layer_tok<100, 100, true>(w2a, b2a, h1, sc1, tid);
    __syncthreads();
    // ---- f = f1 @ w2b + b2b (overwrites dead s2) -------------------------
    layer_tok<100, 50, false>(w2b, b2b, sc1, sc2, tid);
    __syncthreads();

    // ---- wf into registers, then mv = [self_state | wf] ------------------
    {
        float v = 0.f;
        if (tid < GB * 56) {
            int b = tid / 56, c = tid % 56;
            if (c < 6) {
                v = ss[b * 6 + c];
            } else {
                int cc = c - 6;
                const float* fb = sc2 + (b * 50 + cc) * NTOK;
                const float* ab = att + b * NTOK;
                float acc = 0.f;
#pragma unroll
                for (int n = 0; n < NTOK; ++n) acc = fmaf(fb[n], ab[n], acc);
                v = acc;
            }
        }
        __syncthreads();          // f1 (sc1 region) dead; mv may overwrite
        if (tid < GB * 56) mv[tid] = v;
    }
    __syncthreads();

    // ---- final MLP: 56 -> 150 -> 100 -> 100 -> 1 -------------------------
    layer_vec<56, 150, true>(w3a, b3a, mv, ha, tid);
    __syncthreads();
    layer_vec<150, 100, true>(w3b, b3b, ha, hb, tid);
    __syncthreads();
    layer_vec<100, 100, true>(w3c, b3c, hb, hc, tid);
    __syncthreads();

    if (tid < GB) {
        const float* ib = hc + tid * 100;
        float acc = b3d[0];
#pragma unroll 8
        for (int k = 0; k < 100; ++k) acc = fmaf(ib[k], w3d[k], acc);
        outp[b0 + tid] = acc;
    }
}

extern "C" void kernel_launch(void* const* d_in, const int* in_sizes, int n_in,
                              void* d_out, int out_size, void* d_ws, size_t ws_size,
                              hipStream_t stream)
{
    const float* x   = (const float*)d_in[0];
    const float* w1a = (const float*)d_in[1];
    const float* b1a = (const float*)d_in[2];
    const float* w1b = (const float*)d_in[3];
    const float* b1b = (const float*)d_in[4];
    const float* wa0 = (const float*)d_in[5];
    const float* ba0 = (const float*)d_in[6];
    const float* wa1 = (const float*)d_in[7];
    const float* ba1 = (const float*)d_in[8];
    const float* wa2 = (const float*)d_in[9];
    const float* ba2 = (const float*)d_in[10];
    const float* w2a = (const float*)d_in[11];
    const float* b2a = (const float*)d_in[12];
    const float* w2b = (const float*)d_in[13];
    const float* b2b = (const float*)d_in[14];
    const float* w3a = (const float*)d_in[15];
    const float* b3a = (const float*)d_in[16];
    const float* w3b = (const float*)d_in[17];
    const float* b3b = (const float*)d_in[18];
    const float* w3c = (const float*)d_in[19];
    const float* b3c = (const float*)d_in[20];
    const float* w3d = (const float*)d_in[21];
    const float* b3d = (const float*)d_in[22];
    float* outp = (float*)d_out;

    const int B = 16384;
    dim3 grid(B / GB), block(NT);
    hipLaunchKernelGGL(vnet_kernel, grid, block, 0, stream,
                       x, w1a, b1a, w1b, b1b, wa0, ba0, wa1, ba1, wa2, ba2,
                       w2a, b2a, w2b, b2b, w3a, b3a, w3b, b3b, w3c, b3c,
                       w3d, b3d, outp);
}

// Round 3
// 753.464 us; speedup vs baseline: 1.6623x; 1.0849x over previous
//
#include <hip/hip_runtime.h>
#include <math.h>

#define NT   256     // threads per block
#define GB   2       // batch elements per block
#define NTOK 20

typedef float f32x2 __attribute__((ext_vector_type(2)));
typedef float f32x4 __attribute__((ext_vector_type(4)));

// LDS arena (floats) — 13040 floats = 52160 B -> 3 blocks/CU (12 waves/CU)
#define OFF_H1   0
#define OFF_B    4000
#define OFF_T1   (OFF_B)          // 6000 floats
#define OFF_SC1  (OFF_B)          // 4000 floats (s1, then f1)
#define OFF_SC2  (OFF_B + 4000)   // 4000 floats (s2, then f)
#define OFF_MV   (OFF_B)          // 112 floats
#define OFF_HA   (OFF_B + 128)    // 300
#define OFF_HB   (OFF_B + 448)    // 200
#define OFF_HC   (OFF_B + 672)    // 200
#define OFF_D    12000
#define OFF_XS   (OFF_D)          // 1040 floats
#define OFF_GQ   (OFF_D)          // 200 floats (overwrites dead xs)
#define OFF_ATT  (OFF_D + 208)    // 40 floats
#define OFF_SS   (OFF_D + 1024)   // 12 floats (self_state, 2 x 6)
#define LDS_FLOATS 13040

// ---------------------------------------------------------------------------
// Per-token layer: out[b][c][n] = act(bias[c] + sum_k in[b][k][n] * W[k][c])
// act = [GB][K][NTOK], out = [GB][OUT][NTOK]; thread <-> (b,c) task.
// Accumulator = 10 x f32x2 -> v_pk_fma_f32 (2 FMA/lane/instr) halves FMA
// issue cycles. Weight scalar broadcast into both halves is free (op_sel).
// ---------------------------------------------------------------------------
template <int K, int OUT, bool RELU>
__device__ __forceinline__ void layer_tok(const float* __restrict__ W,
                                          const float* __restrict__ bias,
                                          const float* act, float* out, int tid)
{
    for (int t = tid; t < GB * OUT; t += NT) {
        int b = t / OUT, c = t % OUT;
        f32x2 acc[10];
#pragma unroll
        for (int i = 0; i < 10; ++i) acc[i] = (f32x2){0.f, 0.f};
        const float* ab = act + b * K * NTOK;
        const float* wc = W + c;
#pragma unroll 8
        for (int k = 0; k < K; ++k) {
            float w = wc[k * OUT];
            f32x2 wv = {w, w};
            const f32x4* a4 = reinterpret_cast<const f32x4*>(ab + k * NTOK);
#pragma unroll
            for (int i = 0; i < 5; ++i) {
                f32x4 v = a4[i];
                acc[2 * i]     = __builtin_elementwise_fma(v.lo, wv, acc[2 * i]);
                acc[2 * i + 1] = __builtin_elementwise_fma(v.hi, wv, acc[2 * i + 1]);
            }
        }
        float bs = bias[c];
        f32x2 bb = {bs, bs};
        f32x2 zz = {0.f, 0.f};
        float* ob = out + (b * OUT + c) * NTOK;
#pragma unroll
        for (int i = 0; i < 5; ++i) {
            f32x2 lo = acc[2 * i] + bb;
            f32x2 hi = acc[2 * i + 1] + bb;
            if (RELU) {
                lo = __builtin_elementwise_max(lo, zz);
                hi = __builtin_elementwise_max(hi, zz);
            }
            f32x4 o;
            o.lo = lo; o.hi = hi;
            reinterpret_cast<f32x4*>(ob)[i] = o;
        }
    }
}

// Per-batch vector layer: out[b][c] = act(bias[c] + sum_k in[b][k] * W[k][c])
// K must be even. Packed: input pairs via b64 LDS reads, weight pairs via two
// dword loads landing in an adjacent reg pair.
template <int K, int OUT, bool RELU>
__device__ __forceinline__ void layer_vec(const float* __restrict__ W,
                                          const float* __restrict__ bias,
                                          const float* in, float* out, int tid)
{
    for (int t = tid; t < GB * OUT; t += NT) {
        int b = t / OUT, c = t % OUT;
        f32x2 acc = {bias[c], 0.f};
        const f32x2* ib = reinterpret_cast<const f32x2*>(in + b * K);
        const float* wc = W + c;
#pragma unroll 4
        for (int k = 0; k < K / 2; ++k) {
            f32x2 wv = {wc[(2 * k) * OUT], wc[(2 * k + 1) * OUT]};
            acc = __builtin_elementwise_fma(ib[k], wv, acc);
        }
        float r = acc.x + acc.y;
        out[t] = RELU ? fmaxf(r, 0.f) : r;
    }
}

__global__ __launch_bounds__(NT)
void vnet_kernel(const float* __restrict__ x,
                 const float* __restrict__ w1a, const float* __restrict__ b1a,
                 const float* __restrict__ w1b, const float* __restrict__ b1b,
                 const float* __restrict__ wa0, const float* __restrict__ ba0,
                 const float* __restrict__ wa1, const float* __restrict__ ba1,
                 const float* __restrict__ wa2, const float* __restrict__ ba2,
                 const float* __restrict__ w2a, const float* __restrict__ b2a,
                 const float* __restrict__ w2b, const float* __restrict__ b2b,
                 const float* __restrict__ w3a, const float* __restrict__ b3a,
                 const float* __restrict__ w3b, const float* __restrict__ b3b,
                 const float* __restrict__ w3c, const float* __restrict__ b3c,
                 const float* __restrict__ w3d, const float* __restrict__ b3d,
                 float* __restrict__ outp)
{
    __shared__ __align__(16) float lds[LDS_FLOATS];
    float* xs  = lds + OFF_XS;
    float* t1  = lds + OFF_T1;
    float* h1  = lds + OFF_H1;
    float* gq  = lds + OFF_GQ;
    float* sc1 = lds + OFF_SC1;
    float* sc2 = lds + OFF_SC2;
    float* att = lds + OFF_ATT;
    float* ss  = lds + OFF_SS;
    float* mv  = lds + OFF_MV;
    float* ha  = lds + OFF_HA;
    float* hb  = lds + OFF_HB;
    float* hc  = lds + OFF_HC;

    const int tid = threadIdx.x;
    const int b0  = blockIdx.x * GB;

    // ---- load + transpose x: xs[b][d][n] = x[b0+b][n][d] -----------------
    const float* xg = x + (size_t)b0 * (NTOK * 13);
    for (int t = tid; t < GB * NTOK * 13; t += NT) {
        int b = t / (NTOK * 13), r = t % (NTOK * 13);
        int n = r / 13, d = r % 13;
        xs[(b * 13 + d) * NTOK + n] = xg[t];   // coalesced read
    }
    __syncthreads();

    // ---- t1 = relu(x@w1a+b1a) -------------------------------------------
    layer_tok<13, 150, true>(w1a, b1a, xs, t1, tid);
    __syncthreads();
    // ---- h1 = relu(t1@w1b+b1b); also stash self_state (xs last use) -----
    layer_tok<150, 100, true>(w1b, b1b, t1, h1, tid);
    if (tid < GB * 6) {                      // ss[b*6+c] = x[b,0,c]
        int b = tid / 6, c = tid % 6;
        ss[tid] = xs[(b * 13 + c) * NTOK + 0];
    }
    __syncthreads();

    // ---- gq = mean over tokens (overwrites dead xs region) ---------------
    for (int t = tid; t < GB * 100; t += NT) {
        const f32x4* hr = reinterpret_cast<const f32x4*>(h1 + t * NTOK);
        f32x4 s4 = hr[0] + hr[1] + hr[2] + hr[3] + hr[4];
        gq[t] = (s4.x + s4.y + s4.z + s4.w) * (1.f / NTOK);
    }
    __syncthreads();

    // ---- s1 = relu([h1 | g] @ wa0 + ba0)  (overwrites dead t1) -----------
    for (int t = tid; t < GB * 100; t += NT) {
        int b = t / 100, c = t % 100;
        float gacc = ba0[c];
        const float* gb_ = gq + b * 100;
        const float* wgc = wa0 + 100 * 100 + c;
#pragma unroll 8
        for (int k = 0; k < 100; ++k)
            gacc = fmaf(gb_[k], wgc[k * 100], gacc);
        f32x2 acc[10];
#pragma unroll
        for (int i = 0; i < 10; ++i) acc[i] = (f32x2){0.f, 0.f};
        const float* ab = h1 + b * 100 * NTOK;
        const float* wc = wa0 + c;
#pragma unroll 8
        for (int k = 0; k < 100; ++k) {
            float w = wc[k * 100];
            f32x2 wv = {w, w};
            const f32x4* a4 = reinterpret_cast<const f32x4*>(ab + k * NTOK);
#pragma unroll
            for (int i = 0; i < 5; ++i) {
                f32x4 v = a4[i];
                acc[2 * i]     = __builtin_elementwise_fma(v.lo, wv, acc[2 * i]);
                acc[2 * i + 1] = __builtin_elementwise_fma(v.hi, wv, acc[2 * i + 1]);
            }
        }
        f32x2 bb = {gacc, gacc};
        f32x2 zz = {0.f, 0.f};
        float* ob = sc1 + (b * 100 + c) * NTOK;
#pragma unroll
        for (int i = 0; i < 5; ++i) {
            f32x2 lo = __builtin_elementwise_max(acc[2 * i] + bb, zz);
            f32x2 hi = __builtin_elementwise_max(acc[2 * i + 1] + bb, zz);
            f32x4 o;
            o.lo = lo; o.hi = hi;
            reinterpret_cast<f32x4*>(ob)[i] = o;
        }
    }
    __syncthreads();

    // ---- s2 = relu(s1 @ wa1 + ba1) ---------------------------------------
    layer_tok<100, 100, true>(wa1, ba1, sc1, sc2, tid);
    __syncthreads();

    // ---- scores = s2 @ wa2 + ba2 -----------------------------------------
    for (int t = tid; t < GB * NTOK; t += NT) {
        int b = t / NTOK, n = t % NTOK;
        float acc = ba2[0];
        const float* sb = sc2 + b * 100 * NTOK + n;
#pragma unroll 8
        for (int c = 0; c < 100; ++c) acc = fmaf(sb[c * NTOK], wa2[c], acc);
        att[t] = acc;
    }
    __syncthreads();

    // ---- softmax over tokens (serial per b; tiny) ------------------------
    if (tid < GB) {
        float* a = att + tid * NTOK;
        float mx = a[0];
#pragma unroll
        for (int n = 1; n < NTOK; ++n) mx = fmaxf(mx, a[n]);
        float s = 0.f;
#pragma unroll
        for (int n = 0; n < NTOK; ++n) { float e = expf(a[n] - mx); a[n] = e; s += e; }
        float inv = 1.f / s;
#pragma unroll
        for (int n = 0; n < NTOK; ++n) a[n] *= inv;
    }
    __syncthreads();

    // ---- f1 = relu(h1 @ w2a + b2a) (overwrites dead s1) ------------------
    layer_tok<100, 100, true>(w2a, b2a, h1, sc1, tid);
    __syncthreads();
    // ---- f = f1 @ w2b + b2b (overwrites dead s2) -------------------------
    layer_tok<100, 50, false>(w2b, b2b, sc1, sc2, tid);
    __syncthreads();

    // ---- wf into registers, then mv = [self_state | wf] ------------------
    {
        float v = 0.f;
        if (tid < GB * 56) {
            int b = tid / 56, c = tid % 56;
            if (c < 6) {
                v = ss[b * 6 + c];
            } else {
                int cc = c - 6;
                const float* fb = sc2 + (b * 50 + cc) * NTOK;
                const float* ab = att + b * NTOK;
                float acc = 0.f;
#pragma unroll
                for (int n = 0; n < NTOK; ++n) acc = fmaf(fb[n], ab[n], acc);
                v = acc;
            }
        }
        __syncthreads();          // f1 (sc1 region) dead; mv may overwrite
        if (tid < GB * 56) mv[tid] = v;
    }
    __syncthreads();

    // ---- final MLP: 56 -> 150 -> 100 -> 100 -> 1 -------------------------
    layer_vec<56, 150, true>(w3a, b3a, mv, ha, tid);
    __syncthreads();
    layer_vec<150, 100, true>(w3b, b3b, ha, hb, tid);
    __syncthreads();
    layer_vec<100, 100, true>(w3c, b3c, hb, hc, tid);
    __syncthreads();

    if (tid < GB) {
        const float* ib = hc + tid * 100;
        float acc = b3d[0];
#pragma unroll 8
        for (int k = 0; k < 100; ++k) acc = fmaf(ib[k], w3d[k], acc);
        outp[b0 + tid] = acc;
    }
}

extern "C" void kernel_launch(void* const* d_in, const int* in_sizes, int n_in,
                              void* d_out, int out_size, void* d_ws, size_t ws_size,
                              hipStream_t stream)
{
    const float* x   = (const float*)d_in[0];
    const float* w1a = (const float*)d_in[1];
    const float* b1a = (const float*)d_in[2];
    const float* w1b = (const float*)d_in[3];
    const float* b1b = (const float*)d_in[4];
    const float* wa0 = (const float*)d_in[5];
    const float* ba0 = (const float*)d_in[6];
    const float* wa1 = (const float*)d_in[7];
    const float* ba1 = (const float*)d_in[8];
    const float* wa2 = (const float*)d_in[9];
    const float* ba2 = (const float*)d_in[10];
    const float* w2a = (const float*)d_in[11];
    const float* b2a = (const float*)d_in[12];
    const float* w2b = (const float*)d_in[13];
    const float* b2b = (const float*)d_in[14];
    const float* w3a = (const float*)d_in[15];
    const float* b3a = (const float*)d_in[16];
    const float* w3b = (const float*)d_in[17];
    const float* b3b = (const float*)d_in[18];
    const float* w3c = (const float*)d_in[19];
    const float* b3c = (const float*)d_in[20];
    const float* w3d = (const float*)d_in[21];
    const float* b3d = (const float*)d_in[22];
    float* outp = (float*)d_out;

    const int B = 16384;
    dim3 grid(B / GB), block(NT);
    hipLaunchKernelGGL(vnet_kernel, grid, block, 0, stream,
                       x, w1a, b1a, w1b, b1b, wa0, ba0, wa1, ba1, wa2, ba2,
                       w2a, b2a, w2b, b2b, w3a, b3a, w3b, b3b, w3c, b3c,
                       w3d, b3d, outp);
}

// Round 4
// 617.787 us; speedup vs baseline: 2.0273x; 1.2196x over previous
//
#include <hip/hip_runtime.h>
#include <math.h>

#define NT    256
#define GB    4
#define NTOK  20
#define MT    5          // M tiles: 80 rows / 16
#define WAVES 4

typedef _Float16 f16x8 __attribute__((ext_vector_type(8)));
typedef float    f32x4 __attribute__((ext_vector_type(4)));

// ---- ws layout (halves): transposed, zero-padded fp16 weights W_T[n][kpad]
#define WS_W1A 0        // [160][32]   (N=150,K=13)
#define WS_W1B 5120     // [112][160]  (N=100,K=150)
#define WS_WA0 23040    // [112][128]  (N=100,K=100)  wa0 rows 0..99 (h1 part)
#define WS_WA1 37376    // [112][128]
#define WS_W2A 51712    // [112][128]
#define WS_W2B 66048    // [64][128]   (N=50,K=100)
#define WS_TOTAL 74240

// ---- LDS arena. half-offsets (h) and float-offsets (f). total 18504 dw = 74016 B
#define LH_T1   0        // t1 [80][168]  (later s1/f1 [80][136])
#define LH_S1   0
#define LH_H1   13440    // h1 [80][136]
#define LH_A0   24320    // A0 [80][40]  (later s2 [80][136], later f [80][72])
#define LH_S2   24320
#define LH_F    24320
#define LF_MV   15040    // mv [4*56] f32
#define LF_HA   15264    // ha [4*150]
#define LF_HB   15864    // hb [4*100]
#define LF_HC   16264    // hc [4*100]
#define LF_GQ   17600    // gq [4*100]
#define LF_GB   18000    // gbias [4*100]
#define LF_ATT  18400    // att [80]
#define LF_SS   18480    // self_state [4*6]
#define LDS_DW  18504
#define LDS_BYTES (LDS_DW * 4)

// ---------------------------------------------------------------------------
// prep: W_T[n][k] = (fp16) W[k][N..] with zero padding
// ---------------------------------------------------------------------------
__device__ __forceinline__ void prep_one(const float* __restrict__ src, _Float16* dst,
                                         int local, int N, int K, int Ks)
{
    int n = local / Ks, k = local - n * Ks;
    dst[local] = (_Float16)((n < N && k < K) ? src[k * N + n] : 0.f);
}

__global__ __launch_bounds__(256)
void prep_kernel(const float* __restrict__ w1a, const float* __restrict__ w1b,
                 const float* __restrict__ wa0, const float* __restrict__ wa1,
                 const float* __restrict__ w2a, const float* __restrict__ w2b,
                 _Float16* __restrict__ ws)
{
    int g = blockIdx.x * 256 + threadIdx.x;
    if (g >= WS_TOTAL) return;
    if (g < WS_W1B)      prep_one(w1a, ws + WS_W1A, g - WS_W1A, 150, 13, 32);
    else if (g < WS_WA0) prep_one(w1b, ws + WS_W1B, g - WS_W1B, 100, 150, 160);
    else if (g < WS_WA1) prep_one(wa0, ws + WS_WA0, g - WS_WA0, 100, 100, 128);
    else if (g < WS_W2A) prep_one(wa1, ws + WS_WA1, g - WS_WA1, 100, 100, 128);
    else if (g < WS_W2B) prep_one(w2a, ws + WS_W2A, g - WS_W2A, 100, 100, 128);
    else                 prep_one(w2b, ws + WS_W2B, g - WS_W2B,  50, 100, 128);
}

// ---------------------------------------------------------------------------
// MFMA epilogue: D frag -> LDS fp16, with bias (+optional per-(b,c) gbias) + relu
// C/D mapping (m89-verified): col = lane&15, row = (lane>>4)*4 + reg
// ---------------------------------------------------------------------------
template<bool RELU, int BMODE>
__device__ __forceinline__ void epi_store(f32x4 acc, int mt, int nt, int cl, int kq,
                                          const float* __restrict__ biasg,
                                          const float* gbias, int Ncols,
                                          _Float16* C, int Cs)
{
    const int col = nt * 16 + cl;
    float bv = 0.f;
    if (BMODE == 0) bv = (col < Ncols) ? biasg[col] : 0.f;
#pragma unroll
    for (int r = 0; r < 4; ++r) {
        const int row = mt * 16 + kq * 4 + r;
        float y = acc[r];
        if (BMODE == 1) {
            int b = row / NTOK;
            y += (col < Ncols) ? gbias[b * 100 + col] : 0.f;
        } else {
            y += bv;
        }
        if (RELU) y = fmaxf(y, 0.f);
        C[row * Cs + col] = (_Float16)y;
    }
}

// ---------------------------------------------------------------------------
// Tiled GEMM: C[80][..] = act(A[80][K] @ B[K][N] + bias)
// A in LDS [row][As] fp16 (16B-aligned rows). B = W_T[n][Bs] fp16 in global
// (L2-resident). Per-wave: tiles t = wv, wv+4, ... processed in pairs for
// MFMA dep-chain ILP. A-frag: ds_read_b128; B-frag: global dwordx4.
// ---------------------------------------------------------------------------
template<int KT, int NTL, bool RELU, int BMODE>
__device__ __forceinline__ void gemm_tok(const _Float16* A, const int As,
                                         const _Float16* __restrict__ BT, const int Bs,
                                         const float* __restrict__ biasg,
                                         const float* gbias, const int Ncols,
                                         _Float16* C, const int Cs,
                                         const int wv, const int lane)
{
    const int cl = lane & 15, kq = lane >> 4;
    const int T = MT * NTL;
    for (int p = wv; p < T; p += 2 * WAVES) {
        const int t0 = p, t1 = p + WAVES;
        const bool two = (t1 < T);
        const int mt0 = t0 / NTL, nt0 = t0 % NTL;
        const int mt1 = two ? t1 / NTL : 0, nt1 = two ? t1 % NTL : 0;
        const _Float16* A0p = A  + (mt0 * 16 + cl) * As + kq * 8;
        const _Float16* B0p = BT + (nt0 * 16 + cl) * Bs + kq * 8;
        const _Float16* A1p = A  + (mt1 * 16 + cl) * As + kq * 8;
        const _Float16* B1p = BT + (nt1 * 16 + cl) * Bs + kq * 8;
        f32x4 acc0 = {0.f, 0.f, 0.f, 0.f};
        f32x4 acc1 = {0.f, 0.f, 0.f, 0.f};
#pragma unroll
        for (int kt = 0; kt < KT; ++kt) {
            f16x8 a0 = *(const f16x8*)(A0p + kt * 32);
            f16x8 b0 = *(const f16x8*)(B0p + kt * 32);
            acc0 = __builtin_amdgcn_mfma_f32_16x16x32_f16(a0, b0, acc0, 0, 0, 0);
            if (two) {
                f16x8 a1 = *(const f16x8*)(A1p + kt * 32);
                f16x8 b1 = *(const f16x8*)(B1p + kt * 32);
                acc1 = __builtin_amdgcn_mfma_f32_16x16x32_f16(a1, b1, acc1, 0, 0, 0);
            }
        }
        epi_store<RELU, BMODE>(acc0, mt0, nt0, cl, kq, biasg, gbias, Ncols, C, Cs);
        if (two)
            epi_store<RELU, BMODE>(acc1, mt1, nt1, cl, kq, biasg, gbias, Ncols, C, Cs);
    }
}

// Per-batch fp32 vector layer (final MLP): out[b][c] = act(b[c] + sum in[b][k] W[k][c])
template<int K, int OUT, bool RELU>
__device__ __forceinline__ void layer_vec(const float* __restrict__ W,
                                          const float* __restrict__ bias,
                                          const float* in, float* out, int tid)
{
    for (int t = tid; t < GB * OUT; t += NT) {
        int b = t / OUT, c = t % OUT;
        float acc = bias[c];
        const float* ib = in + b * K;
#pragma unroll 8
        for (int k = 0; k < K; ++k) acc = fmaf(ib[k], W[k * OUT + c], acc);
        out[t] = RELU ? fmaxf(acc, 0.f) : acc;
    }
}

__global__ __launch_bounds__(NT, 2)
void vnet_kernel(const float* __restrict__ x,
                 const float* __restrict__ b1a, const float* __restrict__ b1b,
                 const float* __restrict__ wa0, const float* __restrict__ ba0,
                 const float* __restrict__ ba1,
                 const float* __restrict__ wa2, const float* __restrict__ ba2,
                 const float* __restrict__ b2a, const float* __restrict__ b2b,
                 const float* __restrict__ w3a, const float* __restrict__ b3a,
                 const float* __restrict__ w3b, const float* __restrict__ b3b,
                 const float* __restrict__ w3c, const float* __restrict__ b3c,
                 const float* __restrict__ w3d, const float* __restrict__ b3d,
                 const _Float16* __restrict__ wsh,
                 float* __restrict__ outp)
{
    extern __shared__ float lds_f[];
    _Float16* lds_h = (_Float16*)lds_f;

    const int tid  = threadIdx.x;
    const int lane = tid & 63, wv = tid >> 6;
    const int b0   = blockIdx.x * GB;

    // ---- P0: zero arena (pad-column invariants depend on this) -----------
    for (int i = tid; i < LDS_DW; i += NT) lds_f[i] = 0.f;
    __syncthreads();

    // ---- P1: x -> A0 fp16 [80][40] (cols 13..39 zero); stash self_state --
    const float* xg = x + (size_t)b0 * (NTOK * 13);
    _Float16* A0 = lds_h + LH_A0;
    for (int t = tid; t < GB * NTOK * 13; t += NT) {
        int row = t / 13, d = t - row * 13;
        A0[row * 40 + d] = (_Float16)xg[t];
    }
    for (int t = tid; t < GB * NTOK * 27; t += NT) {
        int row = t / 27, c = 13 + (t - row * 27);
        A0[row * 40 + c] = (_Float16)0.f;
    }
    float* ss = lds_f + LF_SS;
    if (tid < GB * 6) {
        int b = tid / 6, d = tid - b * 6;
        ss[tid] = xg[b * (NTOK * 13) + d];   // x[b,0,d]
    }
    __syncthreads();

    // ---- P2: t1 = relu(x @ w1a + b1a)   [80][168], K=32(13), N=160(150) --
    gemm_tok<1, 10, true, 0>(A0, 40, wsh + WS_W1A, 32, b1a, nullptr, 150,
                             lds_h + LH_T1, 168, wv, lane);
    __syncthreads();

    // ---- P3: h1 = relu(t1 @ w1b + b1b)  [80][136], K=160(150), N=112(100)
    gemm_tok<5, 7, true, 0>(lds_h + LH_T1, 168, wsh + WS_W1B, 160, b1b, nullptr, 100,
                            lds_h + LH_H1, 136, wv, lane);
    __syncthreads();

    // ---- P4: gq = mean_n h1 ; re-zero Z1 (s1/f1 pad-col invariant) -------
    const _Float16* h1 = lds_h + LH_H1;
    float* gq = lds_f + LF_GQ;
    for (int t = tid; t < GB * 100; t += NT) {
        int b = t / 100, c = t - b * 100;
        float s = 0.f;
#pragma unroll
        for (int n = 0; n < NTOK; ++n) s += (float)h1[(b * NTOK + n) * 136 + c];
        gq[t] = s * (1.f / NTOK);
    }
    for (int i = tid; i < 5440; i += NT) lds_f[i] = 0.f;
    __syncthreads();

    // ---- P5: gbias[b][c] = ba0[c] + sum_k gq[b][k] * wa0[100+k][c] -------
    float* gbias = lds_f + LF_GB;
    for (int t = tid; t < GB * 100; t += NT) {
        int b = t / 100, c = t - b * 100;
        float acc = ba0[c];
        const float* gb_ = gq + b * 100;
        const float* wg  = wa0 + 100 * 100 + c;
#pragma unroll 8
        for (int k = 0; k < 100; ++k) acc = fmaf(gb_[k], wg[k * 100], acc);
        gbias[t] = acc;
    }
    __syncthreads();

    // ---- P6: s1 = relu(h1 @ wa0[0:100] + gbias)  -> Z1 -------------------
    gemm_tok<4, 7, true, 1>(h1, 136, wsh + WS_WA0, 128, nullptr, gbias, 100,
                            lds_h + LH_S1, 136, wv, lane);
    __syncthreads();

    // ---- P7: s2 = relu(s1 @ wa1 + ba1)  -> Z3 ----------------------------
    gemm_tok<4, 7, true, 0>(lds_h + LH_S1, 136, wsh + WS_WA1, 128, ba1, nullptr, 100,
                            lds_h + LH_S2, 136, wv, lane);
    __syncthreads();

    // ---- P8: scores (reads s2) ; f1 = relu(h1 @ w2a + b2a) -> Z1 ---------
    float* att = lds_f + LF_ATT;
    const _Float16* s2 = lds_h + LH_S2;
    for (int t = tid; t < GB * NTOK; t += NT) {
        float acc = ba2[0];
#pragma unroll 4
        for (int c = 0; c < 100; ++c) acc = fmaf((float)s2[t * 136 + c], wa2[c], acc);
        att[t] = acc;
    }
    gemm_tok<4, 7, true, 0>(h1, 136, wsh + WS_W2A, 128, b2a, nullptr, 100,
                            lds_h + LH_S1, 136, wv, lane);
    __syncthreads();

    // ---- P9: f = f1 @ w2b + b2b (no relu) -> Z3 ; softmax(att) -----------
    gemm_tok<4, 4, false, 0>(lds_h + LH_S1, 136, wsh + WS_W2B, 128, b2b, nullptr, 50,
                             lds_h + LH_F, 72, wv, lane);
    if (tid < GB) {
        float* a = att + tid * NTOK;
        float mx = a[0];
#pragma unroll
        for (int n = 1; n < NTOK; ++n) mx = fmaxf(mx, a[n]);
        float s = 0.f;
#pragma unroll
        for (int n = 0; n < NTOK; ++n) { float e = expf(a[n] - mx); a[n] = e; s += e; }
        float inv = 1.f / s;
#pragma unroll
        for (int n = 0; n < NTOK; ++n) a[n] *= inv;
    }
    __syncthreads();

    // ---- P10: mv = [self_state | wf],  wf = sum_n f[b,n,:] * attn[b,n] ---
    float* mv = lds_f + LF_MV;
    const _Float16* fh = lds_h + LH_F;
    for (int t = tid; t < GB * 56; t += NT) {
        int b = t / 56, c = t - b * 56;
        float v;
        if (c < 6) {
            v = ss[b * 6 + c];
        } else {
            int cc = c - 6;
            float acc = 0.f;
            const float* ab = att + b * NTOK;
#pragma unroll
            for (int n = 0; n < NTOK; ++n)
                acc = fmaf((float)fh[(b * NTOK + n) * 72 + cc], ab[n], acc);
            v = acc;
        }
        mv[t] = v;
    }
    __syncthreads();

    // ---- P11-14: final MLP 56 -> 150 -> 100 -> 100 -> 1 (fp32) -----------
    layer_vec<56, 150, true>(w3a, b3a, mv, lds_f + LF_HA, tid);
    __syncthreads();
    layer_vec<150, 100, true>(w3b, b3b, lds_f + LF_HA, lds_f + LF_HB, tid);
    __syncthreads();
    layer_vec<100, 100, true>(w3c, b3c, lds_f + LF_HB, lds_f + LF_HC, tid);
    __syncthreads();

    if (tid < GB) {
        const float* ib = lds_f + LF_HC + tid * 100;
        float acc = b3d[0];
#pragma unroll 8
        for (int k = 0; k < 100; ++k) acc = fmaf(ib[k], w3d[k], acc);
        outp[b0 + tid] = acc;
    }
}

extern "C" void kernel_launch(void* const* d_in, const int* in_sizes, int n_in,
                              void* d_out, int out_size, void* d_ws, size_t ws_size,
                              hipStream_t stream)
{
    const float* x   = (const float*)d_in[0];
    const float* w1a = (const float*)d_in[1];
    const float* b1a = (const float*)d_in[2];
    const float* w1b = (const float*)d_in[3];
    const float* b1b = (const float*)d_in[4];
    const float* wa0 = (const float*)d_in[5];
    const float* ba0 = (const float*)d_in[6];
    const float* wa1 = (const float*)d_in[7];
    const float* ba1 = (const float*)d_in[8];
    const float* wa2 = (const float*)d_in[9];
    const float* ba2 = (const float*)d_in[10];
    const float* w2a = (const float*)d_in[11];
    const float* b2a = (const float*)d_in[12];
    const float* w2b = (const float*)d_in[13];
    const float* b2b = (const float*)d_in[14];
    const float* w3a = (const float*)d_in[15];
    const float* b3a = (const float*)d_in[16];
    const float* w3b = (const float*)d_in[17];
    const float* b3b = (const float*)d_in[18];
    const float* w3c = (const float*)d_in[19];
    const float* b3c = (const float*)d_in[20];
    const float* w3d = (const float*)d_in[21];
    const float* b3d = (const float*)d_in[22];
    float* outp = (float*)d_out;
    _Float16* wsh = (_Float16*)d_ws;

    // allow >64KB dynamic LDS (74016 B) — host-side attr, capture-safe
    hipFuncSetAttribute((const void*)vnet_kernel,
                        hipFuncAttributeMaxDynamicSharedMemorySize, LDS_BYTES);

    // 1) weight convert/transpose/pad into ws (fp16)
    hipLaunchKernelGGL(prep_kernel, dim3((WS_TOTAL + 255) / 256), dim3(256), 0, stream,
                       w1a, w1b, wa0, wa1, w2a, w2b, wsh);

    // 2) fused network
    const int B = 16384;
    hipLaunchKernelGGL(vnet_kernel, dim3(B / GB), dim3(NT), LDS_BYTES, stream,
                       x, b1a, b1b, wa0, ba0, ba1, wa2, ba2, b2a, b2b,
                       w3a, b3a, w3b, b3b, w3c, b3c, w3d, b3d, wsh, outp);
}

// Round 6
// 269.169 us; speedup vs baseline: 4.6531x; 2.2952x over previous
//
#include <hip/hip_runtime.h>
#include <math.h>

#define NT     512
#define NWAVES 8
#define GB     4
#define NTOK   20

typedef _Float16 f16x8 __attribute__((ext_vector_type(8)));
typedef float    f32x4 __attribute__((ext_vector_type(4)));

// ---- ws layout (halves): transposed, zero-padded fp16 weights W_T[n][kpad]
#define WS_W1A 0        // [160][32]   (N=150,K=13)
#define WS_W1B 5120     // [112][160]  (N=100,K=150)
#define WS_WA0 23040    // [112][128]  (N=100,K=100)  wa0 rows 0..99 (h1 part)
#define WS_WA1 37376    // [112][128]
#define WS_W2A 51712    // [112][128]
#define WS_W2B 66048    // [64][128]   (N=50,K=100)
#define WS_W3A 74240    // [160][64]   (N=150,K=56)
#define WS_W3B 84480    // [112][160]  (N=100,K=150)
#define WS_W3C 102400   // [112][128]  (N=100,K=100)
#define WS_TOTAL 116736

// ---- LDS arena: 3 fp16 regions + small f32 scalar block = 74016 B
#define LH_R1   0        // [80][136] : A0 (head) -> h1 -> mv/ha/hb (tail)
#define LH_R2   10880    // [80][168] : t1 -> s1 -> f1 -> hc (tail)
#define LH_R3   24320    // [80][136] : s2 -> f[80][72]
#define LH_MV   (LH_R1 + 0)      // [16][72]
#define LH_HA   (LH_R1 + 2048)   // [16][168]
#define LH_HB   (LH_R1 + 5120)   // [16][136]
#define LH_HC   (LH_R2 + 0)      // [16][136]
#define LF_GQ   17600    // 400 f32
#define LF_GB   18000    // 400 f32
#define LF_ATT  18400    // 80 f32
#define LF_SS   18480    // 24 f32
#define LDS_DW  18504
#define LDS_BYTES (LDS_DW * 4)

// ---------------------------------------------------------------------------
// prep: W_T[n][k] = (fp16) W[k][N..], zero-padded in both n and k
// ---------------------------------------------------------------------------
__device__ __forceinline__ void prep_one(const float* __restrict__ src, _Float16* dst,
                                         int local, int N, int K, int Ks)
{
    int n = local / Ks, k = local - n * Ks;
    dst[local] = (_Float16)((n < N && k < K) ? src[k * N + n] : 0.f);
}

__global__ __launch_bounds__(256)
void prep_kernel(const float* __restrict__ w1a, const float* __restrict__ w1b,
                 const float* __restrict__ wa0, const float* __restrict__ wa1,
                 const float* __restrict__ w2a, const float* __restrict__ w2b,
                 const float* __restrict__ w3a, const float* __restrict__ w3b,
                 const float* __restrict__ w3c,
                 _Float16* __restrict__ ws)
{
    int g = blockIdx.x * 256 + threadIdx.x;
    if (g >= WS_TOTAL) return;
    if (g < WS_W1B)      prep_one(w1a, ws + WS_W1A, g - WS_W1A, 150, 13, 32);
    else if (g < WS_WA0) prep_one(w1b, ws + WS_W1B, g - WS_W1B, 100, 150, 160);
    else if (g < WS_WA1) prep_one(wa0, ws + WS_WA0, g - WS_WA0, 100, 100, 128);
    else if (g < WS_W2A) prep_one(wa1, ws + WS_WA1, g - WS_WA1, 100, 100, 128);
    else if (g < WS_W2B) prep_one(w2a, ws + WS_W2A, g - WS_W2A, 100, 100, 128);
    else if (g < WS_W3A) prep_one(w2b, ws + WS_W2B, g - WS_W2B,  50, 100, 128);
    else if (g < WS_W3B) prep_one(w3a, ws + WS_W3A, g - WS_W3A, 150,  56, 64);
    else if (g < WS_W3C) prep_one(w3b, ws + WS_W3B, g - WS_W3B, 100, 150, 160);
    else                 prep_one(w3c, ws + WS_W3C, g - WS_W3C, 100, 100, 128);
}

// ---------------------------------------------------------------------------
// MFMA epilogue. C/D mapping (m89-verified): col = lane&15, row = (lane>>4)*4+r
// ---------------------------------------------------------------------------
template<bool RELU, int BMODE>
__device__ __forceinline__ void epi_store(f32x4 acc, int mt, int nt, int cl, int kq,
                                          const float* __restrict__ biasg,
                                          const float* gbias, int Ncols,
                                          _Float16* C, int Cs)
{
    const int col = nt * 16 + cl;
    float bv = 0.f;
    if (BMODE == 0) bv = (col < Ncols) ? biasg[col] : 0.f;
#pragma unroll
    for (int r = 0; r < 4; ++r) {
        const int row = mt * 16 + kq * 4 + r;
        float y = acc[r];
        if (BMODE == 1) {
            int b = row / NTOK;
            y += (col < Ncols) ? gbias[b * 100 + col] : 0.f;
        } else {
            y += bv;
        }
        if (RELU) y = fmaxf(y, 0.f);
        C[row * Cs + col] = (_Float16)y;
    }
}

// ---------------------------------------------------------------------------
// Tiled GEMM, B register-cached per N-tile:
//   work item i -> (nt = i%NTL, m-group g = i/NTL); load KT B-frags once,
//   sweep the group's M-tiles with LDS A-reads + MFMA.
// A: LDS [row][As] fp16.  BT: global W_T[n][Bs] fp16 (L2-hot, zero-padded).
// ---------------------------------------------------------------------------
template<int KT, int NTL, int MTN, bool RELU, int BMODE>
__device__ __forceinline__ void gemm_tok(const _Float16* A, const int As,
                                         const _Float16* __restrict__ BT, const int Bs,
                                         const float* __restrict__ biasg,
                                         const float* gbias, const int Ncols,
                                         _Float16* C, const int Cs,
                                         const int wv, const int lane)
{
    const int cl = lane & 15, kq = lane >> 4;
    constexpr int MH = (MTN >= 4) ? 2 : 1;        // split M-tiles into MH groups
    constexpr int ITEMS = NTL * MH;
    constexpr int MC = (MTN + MH - 1) / MH;       // tiles per group (last clipped)
    for (int i = wv; i < ITEMS; i += NWAVES) {
        const int nt = i % NTL, g = i / NTL;
        const int mt0 = g * MC;
        const _Float16* Bp = BT + (nt * 16 + cl) * Bs + kq * 8;
        f16x8 bf[KT];
#pragma unroll
        for (int kt = 0; kt < KT; ++kt) bf[kt] = *(const f16x8*)(Bp + kt * 32);
#pragma unroll
        for (int mm = 0; mm < MC; ++mm) {
            const int mt = mt0 + mm;
            if (mt >= MTN) break;
            const _Float16* Ap = A + (mt * 16 + cl) * As + kq * 8;
            f16x8 af[KT];
#pragma unroll
            for (int kt = 0; kt < KT; ++kt) af[kt] = *(const f16x8*)(Ap + kt * 32);
            f32x4 acc = {0.f, 0.f, 0.f, 0.f};
#pragma unroll
            for (int kt = 0; kt < KT; ++kt)
                acc = __builtin_amdgcn_mfma_f32_16x16x32_f16(af[kt], bf[kt], acc, 0, 0, 0);
            epi_store<RELU, BMODE>(acc, mt, nt, cl, kq, biasg, gbias, Ncols, C, Cs);
        }
    }
}

__global__ __launch_bounds__(NT, 4)
void vnet_kernel(const float* __restrict__ x,
                 const float* __restrict__ b1a, const float* __restrict__ b1b,
                 const float* __restrict__ wa0, const float* __restrict__ ba0,
                 const float* __restrict__ ba1,
                 const float* __restrict__ wa2, const float* __restrict__ ba2,
                 const float* __restrict__ b2a, const float* __restrict__ b2b,
                 const float* __restrict__ b3a, const float* __restrict__ b3b,
                 const float* __restrict__ b3c,
                 const float* __restrict__ w3d, const float* __restrict__ b3d,
                 const _Float16* __restrict__ wsh,
                 float* __restrict__ outp)
{
    extern __shared__ float lds_f[];
    _Float16* lds_h = (_Float16*)lds_f;

    const int tid  = threadIdx.x;
    const int lane = tid & 63, wv = tid >> 6;
    const int b0   = blockIdx.x * GB;

    _Float16* A0 = lds_h + LH_R1;      // [80][40] at head of R1
    float* ss = lds_f + LF_SS;
    float* gq = lds_f + LF_GQ;
    float* gbias = lds_f + LF_GB;
    float* att = lds_f + LF_ATT;

    // ---- P0: zero arena. Pad-column invariants (and NaN-safety for every
    // garbage region later read as an MFMA A-fragment) depend on this. ------
    for (int i = tid; i < LDS_DW; i += NT) lds_f[i] = 0.f;
    __syncthreads();

    // ---- P1: x -> A0 fp16 [80][40]; stash self_state ---------------------
    const float* xg = x + (size_t)b0 * (NTOK * 13);
    for (int t = tid; t < GB * NTOK * 13; t += NT) {
        int row = t / 13, d = t - row * 13;
        A0[row * 40 + d] = (_Float16)xg[t];
    }
    if (tid < GB * 6) {
        int b = tid / 6, d = tid - b * 6;
        ss[tid] = xg[b * (NTOK * 13) + d];   // x[b,0,d]
    }
    __syncthreads();

    // ---- P2: t1 = relu(x @ w1a + b1a) -> R2 [80][168] --------------------
    gemm_tok<1, 10, 5, true, 0>(A0, 40, wsh + WS_W1A, 32, b1a, nullptr, 150,
                                lds_h + LH_R2, 168, wv, lane);
    __syncthreads();

    // ---- P3: h1 = relu(t1 @ w1b + b1b) -> R1 [80][136] (over A0) ---------
    gemm_tok<5, 7, 5, true, 0>(lds_h + LH_R2, 168, wsh + WS_W1B, 160, b1b, nullptr, 100,
                               lds_h + LH_R1, 136, wv, lane);
    __syncthreads();

    // ---- P4: gq = mean_n h1 ----------------------------------------------
    const _Float16* h1 = lds_h + LH_R1;
    for (int t = tid; t < GB * 100; t += NT) {
        int b = t / 100, c = t - b * 100;
        float s = 0.f;
#pragma unroll
        for (int n = 0; n < NTOK; ++n) s += (float)h1[(b * NTOK + n) * 136 + c];
        gq[t] = s * (1.f / NTOK);
    }
    __syncthreads();

    // ---- P5: gbias[b][c] = ba0[c] + sum_k gq[b][k] * wa0[100+k][c] -------
    for (int t = tid; t < GB * 100; t += NT) {
        int b = t / 100, c = t - b * 100;
        float acc = ba0[c];
        const float* gb_ = gq + b * 100;
        const float* wg  = wa0 + 100 * 100 + c;
#pragma unroll 8
        for (int k = 0; k < 100; ++k) acc = fmaf(gb_[k], wg[k * 100], acc);
        gbias[t] = acc;
    }
    __syncthreads();

    // ---- P6: s1 = relu(h1 @ wa0_lo + gbias) -> R2 (t1 dead), stride 136 --
    gemm_tok<4, 7, 5, true, 1>(h1, 136, wsh + WS_WA0, 128, nullptr, gbias, 100,
                               lds_h + LH_R2, 136, wv, lane);
    __syncthreads();

    // ---- P7: s2 = relu(s1 @ wa1 + ba1) -> R3 -----------------------------
    gemm_tok<4, 7, 5, true, 0>(lds_h + LH_R2, 136, wsh + WS_WA1, 128, ba1, nullptr, 100,
                               lds_h + LH_R3, 136, wv, lane);
    __syncthreads();

    // ---- P8: scores (reads s2); f1 = relu(h1 @ w2a + b2a) -> R2 ----------
    const _Float16* s2 = lds_h + LH_R3;
    for (int t = tid; t < GB * NTOK; t += NT) {
        float acc = ba2[0];
#pragma unroll 4
        for (int c = 0; c < 100; ++c) acc = fmaf((float)s2[t * 136 + c], wa2[c], acc);
        att[t] = acc;
    }
    gemm_tok<4, 7, 5, true, 0>(h1, 136, wsh + WS_W2A, 128, b2a, nullptr, 100,
                               lds_h + LH_R2, 136, wv, lane);
    __syncthreads();

    // ---- P9: f = f1 @ w2b + b2b -> R3 [80][72] (s2 dead); softmax(att) ---
    gemm_tok<4, 4, 5, false, 0>(lds_h + LH_R2, 136, wsh + WS_W2B, 128, b2b, nullptr, 50,
                                lds_h + LH_R3, 72, wv, lane);
    if (tid < GB) {
        float* a = att + tid * NTOK;
        float mx = a[0];
#pragma unroll
        for (int n = 1; n < NTOK; ++n) mx = fmaxf(mx, a[n]);
        float s = 0.f;
#pragma unroll
        for (int n = 0; n < NTOK; ++n) { float e = expf(a[n] - mx); a[n] = e; s += e; }
        float inv = 1.f / s;
#pragma unroll
        for (int n = 0; n < NTOK; ++n) a[n] *= inv;
    }
    __syncthreads();

    // ---- P10: mv16 = [ss | wf] fp16 [16][72] -> R1 head (h1 dead) --------
    _Float16* mv = lds_h + LH_MV;
    const _Float16* fh = lds_h + LH_R3;
    for (int t = tid; t < GB * 56; t += NT) {
        int b = t / 56, c = t - b * 56;
        float v;
        if (c < 6) {
            v = ss[b * 6 + c];
        } else {
            int cc = c - 6;
            float acc = 0.f;
            const float* ab = att + b * NTOK;
#pragma unroll
            for (int n = 0; n < NTOK; ++n)
                acc = fmaf((float)fh[(b * NTOK + n) * 72 + cc], ab[n], acc);
            v = acc;
        }
        mv[b * 72 + c] = (_Float16)v;
    }
    __syncthreads();

    // ---- T1: ha = relu(mv @ w3a + b3a)  [16][168] ------------------------
    gemm_tok<2, 10, 1, true, 0>(mv, 72, wsh + WS_W3A, 64, b3a, nullptr, 150,
                                lds_h + LH_HA, 168, wv, lane);
    __syncthreads();

    // ---- T2: hb = relu(ha @ w3b + b3b)  [16][136] ------------------------
    gemm_tok<5, 7, 1, true, 0>(lds_h + LH_HA, 168, wsh + WS_W3B, 160, b3b, nullptr, 100,
                               lds_h + LH_HB, 136, wv, lane);
    __syncthreads();

    // ---- T3: hc = relu(hb @ w3c + b3c)  [16][136] -> R2 ------------------
    gemm_tok<4, 7, 1, true, 0>(lds_h + LH_HB, 136, wsh + WS_W3C, 128, b3c, nullptr, 100,
                               lds_h + LH_HC, 136, wv, lane);
    __syncthreads();

    // ---- T4: out = hc @ w3d + b3d ----------------------------------------
    if (tid < GB) {
        const _Float16* ib = lds_h + LH_HC + tid * 136;
        float acc = b3d[0];
#pragma unroll 4
        for (int k = 0; k < 100; ++k) acc = fmaf((float)ib[k], w3d[k], acc);
        outp[b0 + tid] = acc;
    }
}

extern "C" void kernel_launch(void* const* d_in, const int* in_sizes, int n_in,
                              void* d_out, int out_size, void* d_ws, size_t ws_size,
                              hipStream_t stream)
{
    const float* x   = (const float*)d_in[0];
    const float* w1a = (const float*)d_in[1];
    const float* b1a = (const float*)d_in[2];
    const float* w1b = (const float*)d_in[3];
    const float* b1b = (const float*)d_in[4];
    const float* wa0 = (const float*)d_in[5];
    const float* ba0 = (const float*)d_in[6];
    const float* wa1 = (const float*)d_in[7];
    const float* ba1 = (const float*)d_in[8];
    const float* wa2 = (const float*)d_in[9];
    const float* ba2 = (const float*)d_in[10];
    const float* w2a = (const float*)d_in[11];
    const float* b2a = (const float*)d_in[12];
    const float* w2b = (const float*)d_in[13];
    const float* b2b = (const float*)d_in[14];
    const float* w3a = (const float*)d_in[15];
    const float* b3a = (const float*)d_in[16];
    const float* w3b = (const float*)d_in[17];
    const float* b3b = (const float*)d_in[18];
    const float* w3c = (const float*)d_in[19];
    const float* b3c = (const float*)d_in[20];
    const float* w3d = (const float*)d_in[21];
    const float* b3d = (const float*)d_in[22];
    float* outp = (float*)d_out;
    _Float16* wsh = (_Float16*)d_ws;

    hipFuncSetAttribute((const void*)vnet_kernel,
                        hipFuncAttributeMaxDynamicSharedMemorySize, LDS_BYTES);

    hipLaunchKernelGGL(prep_kernel, dim3((WS_TOTAL + 255) / 256), dim3(256), 0, stream,
                       w1a, w1b, wa0, wa1, w2a, w2b, w3a, w3b, w3c, wsh);

    const int B = 16384;
    hipLaunchKernelGGL(vnet_kernel, dim3(B / GB), dim3(NT), LDS_BYTES, stream,
                       x, b1a, b1b, wa0, ba0, ba1, wa2, ba2, b2a, b2b,
                       b3a, b3b, b3c, w3d, b3d, wsh, outp);
}

// Round 7
// 203.695 us; speedup vs baseline: 6.1487x; 1.3214x over previous
//
#include <hip/hip_runtime.h>
#include <math.h>

#define NT     512
#define NWAVES 8
#define GB     4
#define NTOK   20

typedef _Float16 f16x8 __attribute__((ext_vector_type(8)));
typedef float    f32x4 __attribute__((ext_vector_type(4)));

// ---- ws layout (halves): transposed, zero-padded fp16 weights W_T[n][kpad]
#define WS_W1A  0        // [160][32]   (N=150,K=13)
#define WS_W1B  5120     // [112][160]  (N=100,K=150)
#define WS_WA0  23040    // [112][128]  (N=100,K=100)  wa0 rows 0..99 (h1 part)
#define WS_WA1  37376    // [112][128]
#define WS_W2A  51712    // [112][128]
#define WS_W2B  66048    // [64][128]   (N=50,K=100)
#define WS_W3A  74240    // [160][64]   (N=150,K=56)
#define WS_W3B  84480    // [112][160]  (N=100,K=150)
#define WS_W3C  102400   // [112][128]  (N=100,K=100)
#define WS_WA0H 116736   // [112][128]  (N=100,K=100)  wa0 rows 100..199 (g part)
#define WS_WA2  131072   // [16][128]   (N=1,  K=100)
#define WS_TOTAL 133120

// ---- LDS arena: 3 fp16 regions + small f32 scalar block = 74016 B
#define LH_R1   0        // [80][136] : A0 (head) -> h1 -> mv/ha/hb (tail)
#define LH_R2   10880    // [80][168] : t1 -> s1 -> f1 -> hc (tail)
#define LH_R3   24320    // [80][136] : gq-strip (head) -> s2 -> f[80][72]
#define LH_MV   (LH_R1 + 0)      // [16][72]
#define LH_HA   (LH_R1 + 2048)   // [16][168]
#define LH_HB   (LH_R1 + 5120)   // [16][136]
#define LH_HC   (LH_R2 + 0)      // [16][136]
#define LH_GQ   (LH_R3 + 0)      // [16][136] fp16 gq strip (rows 0..3 = batches)
#define LF_GB   18000    // 400 f32 (gbias)
#define LF_ATT  18400    // 80 f32
#define LF_SS   18480    // 24 f32
#define LDS_DW  18504
#define LDS_BYTES (LDS_DW * 4)

// ---------------------------------------------------------------------------
// prep: W_T[n][k] = (fp16) W[k][N..], zero-padded in both n and k
// ---------------------------------------------------------------------------
__device__ __forceinline__ void prep_one(const float* __restrict__ src, _Float16* dst,
                                         int local, int N, int K, int Ks)
{
    int n = local / Ks, k = local - n * Ks;
    dst[local] = (_Float16)((n < N && k < K) ? src[k * N + n] : 0.f);
}

__global__ __launch_bounds__(256)
void prep_kernel(const float* __restrict__ w1a, const float* __restrict__ w1b,
                 const float* __restrict__ wa0, const float* __restrict__ wa1,
                 const float* __restrict__ w2a, const float* __restrict__ w2b,
                 const float* __restrict__ w3a, const float* __restrict__ w3b,
                 const float* __restrict__ w3c, const float* __restrict__ wa2,
                 _Float16* __restrict__ ws)
{
    int g = blockIdx.x * 256 + threadIdx.x;
    if (g >= WS_TOTAL) return;
    if (g < WS_W1B)       prep_one(w1a, ws + WS_W1A, g - WS_W1A, 150, 13, 32);
    else if (g < WS_WA0)  prep_one(w1b, ws + WS_W1B, g - WS_W1B, 100, 150, 160);
    else if (g < WS_WA1)  prep_one(wa0, ws + WS_WA0, g - WS_WA0, 100, 100, 128);
    else if (g < WS_W2A)  prep_one(wa1, ws + WS_WA1, g - WS_WA1, 100, 100, 128);
    else if (g < WS_W2B)  prep_one(w2a, ws + WS_W2A, g - WS_W2A, 100, 100, 128);
    else if (g < WS_W3A)  prep_one(w2b, ws + WS_W2B, g - WS_W2B,  50, 100, 128);
    else if (g < WS_W3B)  prep_one(w3a, ws + WS_W3A, g - WS_W3A, 150,  56, 64);
    else if (g < WS_W3C)  prep_one(w3b, ws + WS_W3B, g - WS_W3B, 100, 150, 160);
    else if (g < WS_WA0H) prep_one(w3c, ws + WS_W3C, g - WS_W3C, 100, 100, 128);
    else if (g < WS_WA2)  prep_one(wa0 + 100 * 100, ws + WS_WA0H, g - WS_WA0H, 100, 100, 128);
    else                  prep_one(wa2, ws + WS_WA2, g - WS_WA2, 1, 100, 128);
}

// ---------------------------------------------------------------------------
// MFMA epilogue. C/D mapping (m89-verified): col = lane&15, row = (lane>>4)*4+r
// OMODE 0: fp16 strided LDS store.  1: f32 gbias[row*100+col] (rows<GB).
// 2: f32 att[row] (col 0 only).
// ---------------------------------------------------------------------------
template<bool RELU, int BMODE, int OMODE>
__device__ __forceinline__ void epi_store(f32x4 acc, int mt, int nt, int cl, int kq,
                                          const float* __restrict__ biasg,
                                          const float* gbias, int Ncols,
                                          _Float16* C, int Cs)
{
    const int col = nt * 16 + cl;
    float bv = 0.f;
    if (BMODE == 0) bv = (col < Ncols) ? biasg[col] : 0.f;
#pragma unroll
    for (int r = 0; r < 4; ++r) {
        const int row = mt * 16 + kq * 4 + r;
        float y = acc[r];
        if (BMODE == 1) {
            int b = row / NTOK;
            y += (col < Ncols) ? gbias[b * 100 + col] : 0.f;
        } else {
            y += bv;
        }
        if (RELU) y = fmaxf(y, 0.f);
        if (OMODE == 0) {
            C[row * Cs + col] = (_Float16)y;
        } else if (OMODE == 1) {
            if (row < GB && col < Ncols) ((float*)C)[row * 100 + col] = y;
        } else {
            if (cl == 0 && nt == 0) ((float*)C)[row] = y;
        }
    }
}

// ---------------------------------------------------------------------------
// Tiled GEMM, ILP-first structure:
//   item = one N-tile (nt), wave-assigned; ALL of a wave's B-frags are
//   prefetched up front (independent global loads), then the M-sweep runs
//   fully unrolled so ds_reads pipeline under MFMA chains.
// A: LDS [row][As] fp16.  BT: global W_T[n][Bs] fp16 (L2-hot, zero-padded).
// ---------------------------------------------------------------------------
template<int KT, int NTL, int MTN, bool RELU, int BMODE, int OMODE>
__device__ __forceinline__ void gemm_tok(const _Float16* A, const int As,
                                         const _Float16* __restrict__ BT, const int Bs,
                                         const float* __restrict__ biasg,
                                         const float* gbias, const int Ncols,
                                         _Float16* C, const int Cs,
                                         const int wv, const int lane)
{
    const int cl = lane & 15, kq = lane >> 4;
    constexpr int IPW = (NTL + NWAVES - 1) / NWAVES;
    f16x8 bf[IPW][KT];
#pragma unroll
    for (int ii = 0; ii < IPW; ++ii) {
        const int nt = wv + ii * NWAVES;
        if (nt < NTL) {
            const _Float16* Bp = BT + (nt * 16 + cl) * Bs + kq * 8;
#pragma unroll
            for (int kt = 0; kt < KT; ++kt) bf[ii][kt] = *(const f16x8*)(Bp + kt * 32);
        }
    }
#pragma unroll
    for (int ii = 0; ii < IPW; ++ii) {
        const int nt = wv + ii * NWAVES;
        if (nt >= NTL) break;
#pragma unroll
        for (int mt = 0; mt < MTN; ++mt) {
            const _Float16* Ap = A + (mt * 16 + cl) * As + kq * 8;
            f16x8 af[KT];
#pragma unroll
            for (int kt = 0; kt < KT; ++kt) af[kt] = *(const f16x8*)(Ap + kt * 32);
            f32x4 acc = {0.f, 0.f, 0.f, 0.f};
#pragma unroll
            for (int kt = 0; kt < KT; ++kt)
                acc = __builtin_amdgcn_mfma_f32_16x16x32_f16(af[kt], bf[ii][kt], acc, 0, 0, 0);
            epi_store<RELU, BMODE, OMODE>(acc, mt, nt, cl, kq, biasg, gbias, Ncols, C, Cs);
        }
    }
}

__global__ __launch_bounds__(NT, 4)
void vnet_kernel(const float* __restrict__ x,
                 const float* __restrict__ b1a, const float* __restrict__ b1b,
                 const float* __restrict__ ba0, const float* __restrict__ ba1,
                 const float* __restrict__ ba2,
                 const float* __restrict__ b2a, const float* __restrict__ b2b,
                 const float* __restrict__ b3a, const float* __restrict__ b3b,
                 const float* __restrict__ b3c,
                 const float* __restrict__ w3d, const float* __restrict__ b3d,
                 const _Float16* __restrict__ wsh,
                 float* __restrict__ outp)
{
    extern __shared__ float lds_f[];
    _Float16* lds_h = (_Float16*)lds_f;

    const int tid  = threadIdx.x;
    const int lane = tid & 63, wv = tid >> 6;
    const int b0   = blockIdx.x * GB;

    _Float16* A0  = lds_h + LH_R1;     // [80][40] at head of R1
    _Float16* gqh = lds_h + LH_GQ;     // [16][136] fp16 strip in R3
    float* ss    = lds_f + LF_SS;
    float* gbias = lds_f + LF_GB;
    float* att   = lds_f + LF_ATT;

    // ---- P0: zero arena (pad-column zero + NaN-safety invariants) --------
    for (int i = tid; i < LDS_DW; i += NT) lds_f[i] = 0.f;
    __syncthreads();

    // ---- P1: x -> A0 fp16 [80][40]; stash self_state ---------------------
    const float* xg = x + (size_t)b0 * (NTOK * 13);
    for (int t = tid; t < GB * NTOK * 13; t += NT) {
        int row = t / 13, d = t - row * 13;
        A0[row * 40 + d] = (_Float16)xg[t];
    }
    if (tid < GB * 6) {
        int b = tid / 6, d = tid - b * 6;
        ss[tid] = xg[b * (NTOK * 13) + d];   // x[b,0,d]
    }
    __syncthreads();

    // ---- P2: t1 = relu(x @ w1a + b1a) -> R2 [80][168] --------------------
    gemm_tok<1, 10, 5, true, 0, 0>(A0, 40, wsh + WS_W1A, 32, b1a, nullptr, 150,
                                   lds_h + LH_R2, 168, wv, lane);
    __syncthreads();

    // ---- P3: h1 = relu(t1 @ w1b + b1b) -> R1 [80][136] (over A0) ---------
    gemm_tok<5, 7, 5, true, 0, 0>(lds_h + LH_R2, 168, wsh + WS_W1B, 160, b1b,
                                  nullptr, 100, lds_h + LH_R1, 136, wv, lane);
    __syncthreads();

    // ---- P4: gq fp16 strip [16][136] (rows 0..3) in free R3 head ---------
    const _Float16* h1 = lds_h + LH_R1;
    for (int t = tid; t < GB * 100; t += NT) {
        int b = t / 100, c = t - b * 100;
        float s = 0.f;
#pragma unroll
        for (int n = 0; n < NTOK; ++n) s += (float)h1[(b * NTOK + n) * 136 + c];
        gqh[b * 136 + c] = (_Float16)(s * (1.f / NTOK));
    }
    __syncthreads();

    // ---- P5: gbias[b][c] = ba0[c] + gq[b] @ wa0_hi   (MFMA, f32 out) -----
    gemm_tok<4, 7, 1, false, 0, 1>(gqh, 136, wsh + WS_WA0H, 128, ba0, nullptr, 100,
                                   (_Float16*)gbias, 0, wv, lane);
    __syncthreads();

    // ---- P6: s1 = relu(h1 @ wa0_lo + gbias) -> R2 (t1 dead) --------------
    gemm_tok<4, 7, 5, true, 1, 0>(h1, 136, wsh + WS_WA0, 128, nullptr, gbias, 100,
                                  lds_h + LH_R2, 136, wv, lane);
    __syncthreads();

    // ---- P7: s2 = relu(s1 @ wa1 + ba1) -> R3 (gq strip dead) -------------
    gemm_tok<4, 7, 5, true, 0, 0>(lds_h + LH_R2, 136, wsh + WS_WA1, 128, ba1,
                                  nullptr, 100, lds_h + LH_R3, 136, wv, lane);
    __syncthreads();

    // ---- P8: scores = s2 @ wa2 + ba2 (MFMA, wave 7) ; f1 -> R2 (waves0-6)
    gemm_tok<4, 1, 5, false, 0, 2>(lds_h + LH_R3, 136, wsh + WS_WA2, 128, ba2,
                                   nullptr, 1, (_Float16*)att, 0,
                                   (NWAVES - 1) - wv, lane);
    gemm_tok<4, 7, 5, true, 0, 0>(h1, 136, wsh + WS_W2A, 128, b2a, nullptr, 100,
                                  lds_h + LH_R2, 136, wv, lane);
    __syncthreads();

    // ---- P9: f = f1 @ w2b + b2b -> R3 [80][72] (waves 0-3);
    //          softmax(att) per-b on waves 4-7 --------------------------------
    gemm_tok<4, 4, 5, false, 0, 0>(lds_h + LH_R2, 136, wsh + WS_W2B, 128, b2b,
                                   nullptr, 50, lds_h + LH_R3, 72, wv, lane);
    if (wv >= 4 && lane == 0) {
        int b = wv - 4;
        if (b < GB) {
            float* a = att + b * NTOK;
            float mx = a[0];
#pragma unroll
            for (int n = 1; n < NTOK; ++n) mx = fmaxf(mx, a[n]);
            float s = 0.f;
#pragma unroll
            for (int n = 0; n < NTOK; ++n) { float e = expf(a[n] - mx); a[n] = e; s += e; }
            float inv = 1.f / s;
#pragma unroll
            for (int n = 0; n < NTOK; ++n) a[n] *= inv;
        }
    }
    __syncthreads();

    // ---- P10: mv16 = [ss | wf] fp16 [16][72] -> R1 head (h1 dead) --------
    _Float16* mv = lds_h + LH_MV;
    const _Float16* fh = lds_h + LH_R3;
    for (int t = tid; t < GB * 56; t += NT) {
        int b = t / 56, c = t - b * 56;
        float v;
        if (c < 6) {
            v = ss[b * 6 + c];
        } else {
            int cc = c - 6;
            float acc = 0.f;
            const float* ab = att + b * NTOK;
#pragma unroll
            for (int n = 0; n < NTOK; ++n)
                acc = fmaf((float)fh[(b * NTOK + n) * 72 + cc], ab[n], acc);
            v = acc;
        }
        mv[b * 72 + c] = (_Float16)v;
    }
    __syncthreads();

    // ---- T1: ha = relu(mv @ w3a + b3a)  [16][168] ------------------------
    gemm_tok<2, 10, 1, true, 0, 0>(mv, 72, wsh + WS_W3A, 64, b3a, nullptr, 150,
                                   lds_h + LH_HA, 168, wv, lane);
    __syncthreads();

    // ---- T2: hb = relu(ha @ w3b + b3b)  [16][136] ------------------------
    gemm_tok<5, 7, 1, true, 0, 0>(lds_h + LH_HA, 168, wsh + WS_W3B, 160, b3b,
                                  nullptr, 100, lds_h + LH_HB, 136, wv, lane);
    __syncthreads();

    // ---- T3: hc = relu(hb @ w3c + b3c)  [16][136] -> R2 ------------------
    gemm_tok<4, 7, 1, true, 0, 0>(lds_h + LH_HB, 136, wsh + WS_W3C, 128, b3c,
                                  nullptr, 100, lds_h + LH_HC, 136, wv, lane);
    __syncthreads();

    // ---- T4: out = hc @ w3d + b3d ----------------------------------------
    if (tid < GB) {
        const _Float16* ib = lds_h + LH_HC + tid * 136;
        float acc = b3d[0];
#pragma unroll 4
        for (int k = 0; k < 100; ++k) acc = fmaf((float)ib[k], w3d[k], acc);
        outp[b0 + tid] = acc;
    }
}

extern "C" void kernel_launch(void* const* d_in, const int* in_sizes, int n_in,
                              void* d_out, int out_size, void* d_ws, size_t ws_size,
                              hipStream_t stream)
{
    const float* x   = (const float*)d_in[0];
    const float* w1a = (const float*)d_in[1];
    const float* b1a = (const float*)d_in[2];
    const float* w1b = (const float*)d_in[3];
    const float* b1b = (const float*)d_in[4];
    const float* wa0 = (const float*)d_in[5];
    const float* ba0 = (const float*)d_in[6];
    const float* wa1 = (const float*)d_in[7];
    const float* ba1 = (const float*)d_in[8];
    const float* wa2 = (const float*)d_in[9];
    const float* ba2 = (const float*)d_in[10];
    const float* w2a = (const float*)d_in[11];
    const float* b2a = (const float*)d_in[12];
    const float* w2b = (const float*)d_in[13];
    const float* b2b = (const float*)d_in[14];
    const float* w3a = (const float*)d_in[15];
    const float* b3a = (const float*)d_in[16];
    const float* w3b = (const float*)d_in[17];
    const float* b3b = (const float*)d_in[18];
    const float* w3c = (const float*)d_in[19];
    const float* b3c = (const float*)d_in[20];
    const float* w3d = (const float*)d_in[21];
    const float* b3d = (const float*)d_in[22];
    float* outp = (float*)d_out;
    _Float16* wsh = (_Float16*)d_ws;

    hipFuncSetAttribute((const void*)vnet_kernel,
                        hipFuncAttributeMaxDynamicSharedMemorySize, LDS_BYTES);

    hipLaunchKernelGGL(prep_kernel, dim3((WS_TOTAL + 255) / 256), dim3(256), 0, stream,
                       w1a, w1b, wa0, wa1, w2a, w2b, w3a, w3b, w3c, wa2, wsh);

    const int B = 16384;
    hipLaunchKernelGGL(vnet_kernel, dim3(B / GB), dim3(NT), LDS_BYTES, stream,
                       x, b1a, b1b, ba0, ba1, ba2, b2a, b2b,
                       b3a, b3b, b3c, w3d, b3d, wsh, outp);
}